// Round 5
// baseline (2546.394 us; speedup 1.0000x reference)
//
#include <hip/hip_runtime.h>
#include <math.h>

#define MSZ   1048576ull  // 1024*1024 elements per matrix slot
#define NMAT  33          // matrix 0 = L0, matrices 1..32 = per-batch L
#define PANSZ 61440       // 960*64 shorts per matrix per panel plane
#define NSINK 14
#define NSTAGE 15

__device__ __forceinline__ float frcp(float x){ return __builtin_amdgcn_rcpf(x); }

typedef __attribute__((ext_vector_type(8)))  short  bfrag;   // 8 x bf16 (4 VGPR)
typedef __attribute__((ext_vector_type(8)))  unsigned short u16x8;
typedef __attribute__((ext_vector_type(16))) float  f32x16;  // 32x32 acc

__device__ __forceinline__ unsigned short bf16rn(float x){
  unsigned u = __float_as_uint(x);
  unsigned r = u + 0x7fffu + ((u>>16)&1u);
  return (unsigned short)(r>>16);
}
__device__ __forceinline__ float bf2f(unsigned short h){
  return __uint_as_float(((unsigned)h)<<16);
}

// ---------------------------------------------------------------- setup
__global__ void k_misc(const float* __restrict__ Vc, float* __restrict__ V,
                       const float* __restrict__ W, float* __restrict__ Ws){
  int t = threadIdx.x;
  if(blockIdx.x < 4){
    int i = blockIdx.x*256 + t;
    float4 v = ((const float4*)Vc)[i];
    float mx = fmaxf(fmaxf(v.x,v.y), fmaxf(v.z,v.w));
    float e0=__expf(v.x-mx), e1=__expf(v.y-mx), e2=__expf(v.z-mx), e3=__expf(v.w-mx);
    float is = 1.f/(e0+e1+e2+e3);
    ((float4*)V)[i] = make_float4(e0*is, e1*is, e2*is, e3*is);
  } else {
    int idx = (blockIdx.x-4)*256 + t;
    int i = idx>>10, j = idx&1023;
    float v = 0.f;
    if(i != j){
      float w = (i>j) ? W[i*1024+j] : W[j*1024+i];
      v = 1.f/(1.f+__expf(-w));
    }
    Ws[idx]=v;
  }
}

__global__ void k_pr_y(const float* __restrict__ V, const int* __restrict__ x,
                       float* __restrict__ PrInv, float* __restrict__ y){
  int b = blockIdx.x, t = threadIdx.x;
  __shared__ float red[256];
  float acc = 0.f;
  for(int i=t; i<1024; i+=256){
    int xv = x[b*1024+i];
    float pr = V[i*4+xv];
    PrInv[b*1024+i] = 1.f/pr;
    acc += logf(pr + 1e-7f);
  }
  red[t]=acc; __syncthreads();
  for(int s=128;s>0;s>>=1){ if(t<s) red[t]+=red[t+s]; __syncthreads(); }
  if(t==0) y[b]=red[0];
}

// ---------------------------------------------------------------- sinkhorn + WP
__global__ void __launch_bounds__(256) k_sinkhorn(
    const float* __restrict__ Ec, const float* __restrict__ V,
    const float* __restrict__ Ws, const float* __restrict__ PrInv,
    const int* __restrict__ x, float* __restrict__ mats,
    float* __restrict__ partial){
  int idx = blockIdx.x*256 + threadIdx.x;
  int i = idx>>10, j = idx&1023;
  if(i==0) return;
  int t = threadIdx.x;
  int lane = t & 63, wv = t >> 6;
  __shared__ float sE[256][17];
  float E[16];
  {
    const float4* p = (const float4*)(Ec + (size_t)idx*16);
    float4 q0=p[0], q1=p[1], q2=p[2], q3=p[3];
    E[0]=__expf(q0.x); E[1]=__expf(q0.y); E[2]=__expf(q0.z); E[3]=__expf(q0.w);
    E[4]=__expf(q1.x); E[5]=__expf(q1.y); E[6]=__expf(q1.z); E[7]=__expf(q1.w);
    E[8]=__expf(q2.x); E[9]=__expf(q2.y); E[10]=__expf(q2.z); E[11]=__expf(q2.w);
    E[12]=__expf(q3.x);E[13]=__expf(q3.y);E[14]=__expf(q3.z); E[15]=__expf(q3.w);
  }
  float s0=0.f;
  #pragma unroll
  for(int q=0;q<16;q++) s0+=E[q];
  float is0 = frcp(s0);
  #pragma unroll
  for(int q=0;q<16;q++) E[q]*=is0;
  float av[4], bv[4];
  {
    float4 va = ((const float4*)V)[i];
    av[0]=va.x; av[1]=va.y; av[2]=va.z; av[3]=va.w;
    float4 vb = ((const float4*)V)[j];
    bv[0]=vb.x; bv[1]=vb.y; bv[2]=vb.z; bv[3]=vb.w;
  }
  for(int it=0; it<NSINK; ++it){
    #pragma unroll
    for(int r=0;r<4;r++){
      float rs = E[4*r]+E[4*r+1]+E[4*r+2]+E[4*r+3];
      float sc = av[r]*frcp(rs+1e-7f);
      E[4*r]*=sc; E[4*r+1]*=sc; E[4*r+2]*=sc; E[4*r+3]*=sc;
    }
    #pragma unroll
    for(int c=0;c<4;c++){
      float cs = E[c]+E[4+c]+E[8+c]+E[12+c];
      float sc = bv[c]*frcp(cs+1e-7f);
      E[c]*=sc; E[4+c]*=sc; E[8+c]*=sc; E[12+c]*=sc;
    }
  }
  #pragma unroll
  for(int q=0;q<16;q++) sE[t][q] = fminf(fmaxf(E[q],0.f),1.f);
  float wsij = Ws[idx];
  for(int b=0;b<32;b++){
    int xi = x[b*1024+i];
    int xj = x[b*1024+j];
    float val = sE[t][(xi<<2)+xj] * wsij * PrInv[b*1024+i] * PrInv[b*1024+j];
    if(j!=0)
      mats[(size_t)(1+b)*MSZ + (size_t)(i-1)*1024 + (j-1)] = 1e-7f - val;
    float r = val;
    r += __shfl_down(r,32); r += __shfl_down(r,16); r += __shfl_down(r,8);
    r += __shfl_down(r,4);  r += __shfl_down(r,2);  r += __shfl_down(r,1);
    if(lane==0)
      partial[((size_t)b<<14) + ((size_t)(i-1)<<4) + ((blockIdx.x&3)<<2) + wv] = r;
  }
}

// ---------------------------------------------------------------- L0 build
// Also zeroes the per-stage ready flags (495 ints) each replay.
__global__ void k_l0(const float* __restrict__ Ws, float* __restrict__ mats,
                     unsigned* __restrict__ flags){
  int r = blockIdx.x, t = threadIdx.x;
  if(r < 2){
    int f = r*256 + t;
    if(f < NSTAGE*NMAT) flags[f] = 0;
  }
  float* orow = mats + (size_t)r*1024;
  if(r == 1023){
    float4 o = make_float4(0.f,0.f,0.f,0.f);
    if(t==255) o.w = 1.f;
    ((float4*)orow)[t] = o;
    return;
  }
  const float* wrow = Ws + (size_t)(r+1)*1024;
  float4 v = ((const float4*)wrow)[t];
  __shared__ float red[256];
  red[t] = v.x+v.y+v.z+v.w;
  __syncthreads();
  for(int s=128;s>0;s>>=1){ if(t<s) red[t]+=red[t+s]; __syncthreads(); }
  float rs = red[0];
  float o[4];
  #pragma unroll
  for(int q=0;q<4;q++){
    int c = 4*t+q;
    if(c==r)          o[q] = rs + 1e-7f;
    else if(c < 1023) o[q] = 1e-7f - wrow[c+1];
    else              o[q] = 0.f;
  }
  ((float4*)orow)[t] = make_float4(o[0],o[1],o[2],o[3]);
}

__global__ void k_patch(float* __restrict__ mats, const float* __restrict__ partial){
  int m = blockIdx.y + 1;
  int r = blockIdx.x*256 + threadIdx.x;
  float* A = mats + (size_t)m*MSZ;
  A[(size_t)r*1024 + 1023] = (r==1023) ? 1.f : 0.f;
  if(r < 1023){
    A[(size_t)1023*1024 + r] = 0.f;
    const float* pp = partial + (((size_t)(m-1))<<14) + ((size_t)r<<4);
    float s = 0.f;
    #pragma unroll
    for(int q=0;q<16;q++) s += pp[q];
    A[(size_t)r*1024 + r] = s + 1e-7f;
  }
}

// ------------------------------------------- fused diag LU + MFMA trsm (spin)
// Grid (1+2*nb, NMAT).  Block x==0: 64x64 shuffle LU + logdet + Uinv/Linv
// split-bf16 into FRESH per-stage buffers, then agent-scope release flag.
// (Early return -> isolated regalloc, same shape as R1's fast k_diag.)
// Blocks x>=1: trsm.  A21/A12 global loads are issued BEFORE the spin so HBM
// latency hides under the producer's LU; then acquire-spin, read inverses
// (fresh addresses -> LLC, no stale-L2 risk), 24 MFMAs, store panels.
__global__ void __launch_bounds__(256) k_dtrsm(const float* __restrict__ mats_,
    unsigned short* __restrict__ UiH, unsigned short* __restrict__ UiL,
    unsigned short* __restrict__ LiH, unsigned short* __restrict__ LiL,
    unsigned short* __restrict__ Ah, unsigned short* __restrict__ Al,
    unsigned short* __restrict__ Bh, unsigned short* __restrict__ Bl,
    float* __restrict__ logdet, unsigned* __restrict__ flags, int k){
  int m = blockIdx.y;
  int s = k >> 6;
  size_t ibase = ((size_t)s*NMAT + m)*4096;
  unsigned* flag = flags + s*NMAT + m;
  int t = threadIdx.x;
  int lane = t & 63;

  __shared__ float Us[64*68];
  __shared__ float Ls[64*68];
  __shared__ float rd[64];

  if(blockIdx.x == 0){
    // ---------------- producer: LU + inverses (R1 k_diag body, 256 threads)
    const float* A = mats_ + (size_t)m*MSZ;
    int w = t >> 6;
    if(w==0){
      float row[64];
      const float4* pr = (const float4*)(A + (size_t)(k+lane)*1024 + k);
      #pragma unroll
      for(int q4=0;q4<16;q4++){
        float4 v = pr[q4];
        row[4*q4]=v.x; row[4*q4+1]=v.y; row[4*q4+2]=v.z; row[4*q4+3]=v.w;
      }
      float slog = 0.f;
      #pragma unroll
      for(int c=0;c<64;c++){
        float piv = __shfl(row[c], c);
        slog += logf(fabsf(piv));
        float ip = frcp(piv);
        if(lane==c) rd[c] = ip;
        bool below = lane > c;
        float lic = below ? row[c]*ip : 0.f;
        if(below) row[c] = lic;
        #pragma unroll
        for(int q=c+1;q<64;q++){
          float uq = __shfl(row[q], c);
          row[q] = fmaf(-lic, uq, row[q]);
        }
      }
      #pragma unroll
      for(int q=0;q<64;q++){
        Ls[lane*68+q] = (q<lane) ? row[q] : 0.f;
        Us[lane*68+q] = (q>lane) ? row[q] : 0.f;
      }
      if(lane==0){ if(k==0) logdet[m]=slog; else logdet[m]+=slog; }
    }
    __syncthreads();

    if(w==0){
      // Uinv column `lane` via back substitution
      float x[64];
      #pragma unroll
      for(int q=0;q<64;q++) x[q]=0.f;
      float rj = rd[lane];
      #pragma unroll
      for(int r=63;r>=0;r--){
        float a0=0.f,a1=0.f,a2=0.f,a3=0.f;
        #pragma unroll
        for(int c=(r+1)&~3; c<64; c+=4){
          float4 u = *(const float4*)&Us[r*68+c];
          a0 = fmaf(u.x, x[c],   a0);
          a1 = fmaf(u.y, x[c+1], a1);
          a2 = fmaf(u.z, x[c+2], a2);
          a3 = fmaf(u.w, x[c+3], a3);
        }
        float sv = (a0+a1)+(a2+a3);
        x[r] = (r==lane) ? rj : -sv*rd[r];
      }
      unsigned short* ph = UiH + ibase + (size_t)lane*64;
      unsigned short* pl = UiL + ibase + (size_t)lane*64;
      #pragma unroll
      for(int p8=0;p8<8;p8++){
        u16x8 h8, l8;
        #pragma unroll
        for(int e=0;e<8;e++){
          float v = x[p8*8+e];
          unsigned short h = bf16rn(v);
          h8[e]=h; l8[e]=bf16rn(v - bf2f(h));
        }
        ((u16x8*)ph)[p8]=h8; ((u16x8*)pl)[p8]=l8;
      }
    } else if(w==1){
      // Linv column `lane` via forward substitution (unit diag)
      float x[64];
      #pragma unroll
      for(int q=0;q<64;q++) x[q]=0.f;
      #pragma unroll
      for(int r=0;r<64;r++){
        float a0=0.f,a1=0.f,a2=0.f,a3=0.f;
        #pragma unroll
        for(int c=0; c<((r+3)&~3); c+=4){
          float4 u = *(const float4*)&Ls[r*68+c];
          a0 = fmaf(u.x, x[c],   a0);
          a1 = fmaf(u.y, x[c+1], a1);
          a2 = fmaf(u.z, x[c+2], a2);
          a3 = fmaf(u.w, x[c+3], a3);
        }
        x[r] = (r==lane) ? 1.f : -((a0+a1)+(a2+a3));
      }
      #pragma unroll
      for(int r=0;r<64;r++) Ls[r*68+lane] = x[r];
      unsigned short* ph = LiH + ibase + (size_t)lane*64;
      unsigned short* pl = LiL + ibase + (size_t)lane*64;
      #pragma unroll
      for(int p8=0;p8<8;p8++){
        float4 u0 = *(const float4*)&Ls[lane*68 + p8*8];
        float4 u1 = *(const float4*)&Ls[lane*68 + p8*8 + 4];
        float v[8] = {u0.x,u0.y,u0.z,u0.w,u1.x,u1.y,u1.z,u1.w};
        u16x8 h8, l8;
        #pragma unroll
        for(int e=0;e<8;e++){
          unsigned short h = bf16rn(v[e]);
          h8[e]=h; l8[e]=bf16rn(v[e] - bf2f(h));
        }
        ((u16x8*)ph)[p8]=h8; ((u16x8*)pl)[p8]=l8;
      }
    }
    __syncthreads();   // all inverse stores issued; vmcnt drained per-wave
    if(t==0)
      __hip_atomic_store(flag, 1u, __ATOMIC_RELEASE, __HIP_MEMORY_SCOPE_AGENT);
    return;
  }

  // ---------------- consumer: trsm (R1 k_trsm body + spin)
  const float* A = mats_ + (size_t)m*MSZ;
  int rem = 1024 - (k+64);
  int nb = (rem+127)>>7;
  int bx = (int)blockIdx.x - 1;
  bool aside = bx < nb;
  int r32 = lane&31, hi = lane>>5, wv = t>>6;
  int tile0 = (aside ? bx : bx - nb)*128 + wv*32;
  int rel  = tile0 + r32;
  int relc = min(rel, rem-1);

  const unsigned short* IH = (aside ? UiH : LiH) + ibase;
  const unsigned short* IL = (aside ? UiL : LiL) + ibase;

  // Issue A loads NOW (before the spin) so HBM latency hides under the LU.
  float va[64];
  if(aside){
    const float* src = A + (size_t)(k+64+relc)*1024 + k + hi*8;
    #pragma unroll
    for(int kc=0;kc<4;kc++){
      float4 u0 = *(const float4*)(src + kc*16);
      float4 u1 = *(const float4*)(src + kc*16 + 4);
      va[kc*16+0]=u0.x; va[kc*16+1]=u0.y; va[kc*16+2]=u0.z; va[kc*16+3]=u0.w;
      va[kc*16+4]=u1.x; va[kc*16+5]=u1.y; va[kc*16+6]=u1.z; va[kc*16+7]=u1.w;
    }
  } else {
    const float* src = A + (size_t)(k + hi*8)*1024 + (k+64+relc);
    #pragma unroll
    for(int kc=0;kc<4;kc++)
      #pragma unroll
      for(int e=0;e<8;e++)
        va[kc*16+e] = src[(size_t)(kc*16+e)*1024];
  }

  // spin until inverses published
  if(t==0){
    unsigned f;
    do { f = __hip_atomic_load(flag, __ATOMIC_ACQUIRE, __HIP_MEMORY_SCOPE_AGENT); } while(!f);
  }
  __syncthreads();

  bfrag ah[4], al[4];
  #pragma unroll
  for(int kc=0;kc<4;kc++)
    #pragma unroll
    for(int e=0;e<8;e++){
      float v = va[kc*16+e];
      unsigned short h = bf16rn(v);
      ah[kc][e] = (short)h;
      al[kc][e] = (short)bf16rn(v - bf2f(h));
    }

  f32x16 acc[2];
  #pragma unroll
  for(int ct=0;ct<2;ct++)
    #pragma unroll
    for(int q=0;q<16;q++) acc[ct][q]=0.f;

  #pragma unroll
  for(int kc=0;kc<4;kc++){
    #pragma unroll
    for(int ct=0;ct<2;ct++){
      bfrag bh = *(const bfrag*)(IH + (size_t)(ct*32+r32)*64 + kc*16 + hi*8);
      bfrag bl = *(const bfrag*)(IL + (size_t)(ct*32+r32)*64 + kc*16 + hi*8);
      acc[ct] = __builtin_amdgcn_mfma_f32_32x32x16_bf16(ah[kc], bh, acc[ct], 0,0,0);
      acc[ct] = __builtin_amdgcn_mfma_f32_32x32x16_bf16(ah[kc], bl, acc[ct], 0,0,0);
      acc[ct] = __builtin_amdgcn_mfma_f32_32x32x16_bf16(al[kc], bh, acc[ct], 0,0,0);
    }
  }

  unsigned short* PH = (aside ? Ah : Bh) + (size_t)m*PANSZ;
  unsigned short* PL = (aside ? Al : Bl) + (size_t)m*PANSZ;
  #pragma unroll
  for(int ct=0;ct<2;ct++){
    #pragma unroll
    for(int reg=0;reg<16;reg++){
      int crow = (reg&3) + ((reg>>2)<<3) + (hi<<2);
      int r = tile0 + crow;
      if(r < rem){
        float v = acc[ct][reg];
        unsigned short h = bf16rn(v);
        size_t off = (size_t)r*64 + ct*32 + r32;
        PH[off] = h;
        PL[off] = bf16rn(v - bf2f(h));
      }
    }
  }
}

// Final 64x64 block (k=960): logdet contribution only.
__global__ void __launch_bounds__(64) k_ld(const float* __restrict__ mats,
                                           float* __restrict__ logdet){
  int m = blockIdx.x, t = threadIdx.x;
  const float* A = mats + (size_t)m*MSZ;
  float row[64];
  #pragma unroll
  for(int q=0;q<64;q++)
    row[q] = A[(size_t)(960+t)*1024 + 960 + q];
  float slog = 0.f;
  #pragma unroll
  for(int c=0;c<64;c++){
    float piv = __shfl(row[c], c);
    slog += logf(fabsf(piv));
    float ip = frcp(piv);
    bool below = t > c;
    float lic = below ? row[c]*ip : 0.f;
    #pragma unroll
    for(int q=c+1;q<64;q++){
      float uq = __shfl(row[q], c);
      row[q] = fmaf(-lic, uq, row[q]);
    }
  }
  if(t==0) logdet[m] += slog;
}

// ------------------------------------------------------- MFMA split-bf16 Schur
// A22 -= L21 * U12.  R1 version (no fused tail).
__global__ void __launch_bounds__(256) k_gemm(float* __restrict__ mats,
    const unsigned short* __restrict__ Ah, const unsigned short* __restrict__ Al,
    const unsigned short* __restrict__ Bh, const unsigned short* __restrict__ Bl,
    int k){
  int m = blockIdx.z;
  float* A = mats + (size_t)m*MSZ;
  int rem = 1024 - (k+64);
  int i0rel = blockIdx.y*128;
  int j0rel = blockIdx.x*128;
  __shared__ unsigned short As[2][4096];
  __shared__ unsigned short Bs[2][4096];
  int t = threadIdx.x;
  int lane = t & 63, wvi = t >> 6;
  int wr = wvi >> 1, wc = wvi & 1;

  const unsigned short* pAh = Ah + (size_t)m*PANSZ;
  const unsigned short* pAl = Al + (size_t)m*PANSZ;
  const unsigned short* pBh = Bh + (size_t)m*PANSZ;
  const unsigned short* pBl = Bl + (size_t)m*PANSZ;

  int ldsOff[2];
  bool vA[2], vB[2];
  size_t offA[2], offB[2];
  #pragma unroll
  for(int p=0;p<2;p++){
    int c = t + 256*p;
    int row = c>>2, koct = c&3;
    ldsOff[p] = row*32 + ((koct ^ ((row>>1)&3))<<3);
    vA[p] = (i0rel+row) < rem;
    vB[p] = (j0rel+row) < rem;
    offA[p] = (size_t)(i0rel+row)*64 + koct*8;
    offB[p] = (size_t)(j0rel+row)*64 + koct*8;
  }
  u16x8 z; z = 0;

  #pragma unroll
  for(int p=0;p<2;p++){
    u16x8 ah = vA[p] ? *(const u16x8*)(pAh + offA[p]) : z;
    u16x8 al = vA[p] ? *(const u16x8*)(pAl + offA[p]) : z;
    u16x8 bh = vB[p] ? *(const u16x8*)(pBh + offB[p]) : z;
    u16x8 bl = vB[p] ? *(const u16x8*)(pBl + offB[p]) : z;
    *(u16x8*)&As[0][ldsOff[p]] = ah;
    *(u16x8*)&As[1][ldsOff[p]] = al;
    *(u16x8*)&Bs[0][ldsOff[p]] = bh;
    *(u16x8*)&Bs[1][ldsOff[p]] = bl;
  }
  u16x8 p1[8];
  #pragma unroll
  for(int p=0;p<2;p++){
    p1[4*p+0] = vA[p] ? *(const u16x8*)(pAh + offA[p] + 32) : z;
    p1[4*p+1] = vA[p] ? *(const u16x8*)(pAl + offA[p] + 32) : z;
    p1[4*p+2] = vB[p] ? *(const u16x8*)(pBh + offB[p] + 32) : z;
    p1[4*p+3] = vB[p] ? *(const u16x8*)(pBl + offB[p] + 32) : z;
  }
  __syncthreads();

  f32x16 acc[2][2];
  #pragma unroll
  for(int rt=0;rt<2;rt++)
    #pragma unroll
    for(int ct=0;ct<2;ct++)
      #pragma unroll
      for(int q=0;q<16;q++) acc[rt][ct][q] = 0.f;

  int kgrp = lane >> 5;
  #pragma unroll
  for(int ks=0; ks<2; ks++){
    #pragma unroll
    for(int kc=0;kc<2;kc++){
      int koct = kc*2 + kgrp;
      bfrag ah[2], al[2], bh[2], bl[2];
      #pragma unroll
      for(int rt=0;rt<2;rt++){
        int row = wr*64 + rt*32 + (lane&31);
        int ad = row*32 + ((koct ^ ((row>>1)&3))<<3);
        ah[rt] = *(const bfrag*)&As[0][ad];
        al[rt] = *(const bfrag*)&As[1][ad];
      }
      #pragma unroll
      for(int ct=0;ct<2;ct++){
        int col = wc*64 + ct*32 + (lane&31);
        int ad = col*32 + ((koct ^ ((col>>1)&3))<<3);
        bh[ct] = *(const bfrag*)&Bs[0][ad];
        bl[ct] = *(const bfrag*)&Bs[1][ad];
      }
      #pragma unroll
      for(int rt=0;rt<2;rt++)
        #pragma unroll
        for(int ct=0;ct<2;ct++){
          acc[rt][ct] = __builtin_amdgcn_mfma_f32_32x32x16_bf16(ah[rt], bh[ct], acc[rt][ct], 0,0,0);
          acc[rt][ct] = __builtin_amdgcn_mfma_f32_32x32x16_bf16(ah[rt], bl[ct], acc[rt][ct], 0,0,0);
          acc[rt][ct] = __builtin_amdgcn_mfma_f32_32x32x16_bf16(al[rt], bh[ct], acc[rt][ct], 0,0,0);
        }
    }
    if(ks==0){
      __syncthreads();
      #pragma unroll
      for(int p=0;p<2;p++){
        *(u16x8*)&As[0][ldsOff[p]] = p1[4*p+0];
        *(u16x8*)&As[1][ldsOff[p]] = p1[4*p+1];
        *(u16x8*)&Bs[0][ldsOff[p]] = p1[4*p+2];
        *(u16x8*)&Bs[1][ldsOff[p]] = p1[4*p+3];
      }
      __syncthreads();
    }
  }

  int r0 = k + 64;
  #pragma unroll
  for(int rt=0;rt<2;rt++){
    int rowblk = i0rel + wr*64 + rt*32;
    if(rowblk >= rem) continue;
    #pragma unroll
    for(int ct=0;ct<2;ct++){
      int colblk = j0rel + wc*64 + ct*32;
      if(colblk >= rem) continue;
      int col = r0 + colblk + (lane&31);
      int rbase = r0 + rowblk + ((lane>>5)<<2);
      #pragma unroll
      for(int reg=0;reg<16;reg++){
        int row = rbase + (reg&3) + ((reg>>2)<<3);
        float* pc = A + (size_t)row*1024 + col;
        *pc -= acc[rt][ct][reg];
      }
    }
  }
}

__global__ void k_final(const float* __restrict__ y, const float* __restrict__ logdet,
                        float* __restrict__ out){
  int b = threadIdx.x;
  if(b<32) out[b] = y[b] + logdet[1+b] - logdet[0];
}

// ---------------------------------------------------------------- launch
extern "C" void kernel_launch(void* const* d_in, const int* in_sizes, int n_in,
                              void* d_out, int out_size, void* d_ws, size_t ws_size,
                              hipStream_t stream){
  (void)in_sizes; (void)n_in; (void)out_size; (void)ws_size;
  const int*   x  = (const int*)d_in[0];
  const float* W  = (const float*)d_in[1];
  const float* Vc = (const float*)d_in[2];
  const float* Ec = (const float*)d_in[3];
  float* out = (float*)d_out;

  char* p = (char*)d_ws;
  auto alloc = [&](size_t bytes)->char*{ char* r = p; p += (bytes+255)&~(size_t)255; return r; };
  float* mats   = (float*)alloc((size_t)NMAT*MSZ*4);              // 138.4 MB
  float* Ws     = (float*)alloc(1048576ull*4);
  unsigned short* Ah = (unsigned short*)alloc((size_t)NMAT*PANSZ*2);
  unsigned short* Al = (unsigned short*)alloc((size_t)NMAT*PANSZ*2);
  unsigned short* Bh = (unsigned short*)alloc((size_t)NMAT*PANSZ*2);
  unsigned short* Bl = (unsigned short*)alloc((size_t)NMAT*PANSZ*2);
  // per-stage inverse buffers (fresh addresses per stage: no stale-L2 risk)
  unsigned short* UiH = (unsigned short*)alloc((size_t)NSTAGE*NMAT*4096*2);  // 4 MB
  unsigned short* UiL = (unsigned short*)alloc((size_t)NSTAGE*NMAT*4096*2);
  unsigned short* LiH = (unsigned short*)alloc((size_t)NSTAGE*NMAT*4096*2);
  unsigned short* LiL = (unsigned short*)alloc((size_t)NSTAGE*NMAT*4096*2);
  float* V      = (float*)alloc(4096*4);
  float* PrInv  = (float*)alloc(32768*4);
  float* partial= (float*)alloc((size_t)32*16384*4);              // 2 MB
  float* y      = (float*)alloc(256);
  float* logdet = (float*)alloc(256);
  unsigned* flags = (unsigned*)alloc(NSTAGE*NMAT*4);

  k_misc<<<4100,256,0,stream>>>(Vc, V, W, Ws);
  k_pr_y<<<32,256,0,stream>>>(V, x, PrInv, y);
  k_sinkhorn<<<4096,256,0,stream>>>(Ec, V, Ws, PrInv, x, mats, partial);
  k_l0<<<1024,256,0,stream>>>(Ws, mats, flags);
  k_patch<<<dim3(4,32),256,0,stream>>>(mats, partial);

  for(int s=0;s<NSTAGE;s++){
    int k = 64*s;
    int rem = 1024 - (k+64);
    int nb = (rem+127)/128;
    k_dtrsm<<<dim3(1+2*nb,NMAT),256,0,stream>>>(mats, UiH,UiL,LiH,LiL,
                                                Ah,Al,Bh,Bl, logdet, flags, k);
    int nt = (rem+127)/128;
    k_gemm<<<dim3(nt,nt,NMAT),256,0,stream>>>(mats, Ah,Al,Bh,Bl, k);
  }
  k_ld<<<NMAT,64,0,stream>>>(mats, logdet);
  k_final<<<1,32,0,stream>>>(y, logdet, out);
}

// Round 6
// 1649.835 us; speedup vs baseline: 1.5434x; 1.5434x over previous
//
#include <hip/hip_runtime.h>
#include <math.h>

#define MSZ    1048576ull  // 1024*1024 elements per matrix slot
#define NMAT   33          // matrix 0 = L0, matrices 1..32 = per-batch L
#define PANSZ  114688      // 896*128 shorts per matrix per panel plane
#define NSINK  14

__device__ __forceinline__ float frcp(float x){ return __builtin_amdgcn_rcpf(x); }

typedef __attribute__((ext_vector_type(8)))  short  bfrag;   // 8 x bf16 (4 VGPR)
typedef __attribute__((ext_vector_type(8)))  unsigned short u16x8;
typedef __attribute__((ext_vector_type(16))) float  f32x16;  // 32x32 acc

__device__ __forceinline__ unsigned short bf16rn(float x){
  unsigned u = __float_as_uint(x);
  unsigned r = u + 0x7fffu + ((u>>16)&1u);
  return (unsigned short)(r>>16);
}
__device__ __forceinline__ float bf2f(unsigned short h){
  return __uint_as_float(((unsigned)h)<<16);
}

// ---------------------------------------------------------------- setup
__global__ void k_misc(const float* __restrict__ Vc, float* __restrict__ V,
                       const float* __restrict__ W, float* __restrict__ Ws){
  int t = threadIdx.x;
  if(blockIdx.x < 4){
    int i = blockIdx.x*256 + t;
    float4 v = ((const float4*)Vc)[i];
    float mx = fmaxf(fmaxf(v.x,v.y), fmaxf(v.z,v.w));
    float e0=__expf(v.x-mx), e1=__expf(v.y-mx), e2=__expf(v.z-mx), e3=__expf(v.w-mx);
    float is = 1.f/(e0+e1+e2+e3);
    ((float4*)V)[i] = make_float4(e0*is, e1*is, e2*is, e3*is);
  } else {
    int idx = (blockIdx.x-4)*256 + t;
    int i = idx>>10, j = idx&1023;
    float v = 0.f;
    if(i != j){
      float w = (i>j) ? W[i*1024+j] : W[j*1024+i];
      v = 1.f/(1.f+__expf(-w));
    }
    Ws[idx]=v;
  }
}

__global__ void k_pr_y(const float* __restrict__ V, const int* __restrict__ x,
                       float* __restrict__ PrInv, float* __restrict__ y){
  int b = blockIdx.x, t = threadIdx.x;
  __shared__ float red[256];
  float acc = 0.f;
  for(int i=t; i<1024; i+=256){
    int xv = x[b*1024+i];
    float pr = V[i*4+xv];
    PrInv[b*1024+i] = 1.f/pr;
    acc += logf(pr + 1e-7f);
  }
  red[t]=acc; __syncthreads();
  for(int s=128;s>0;s>>=1){ if(t<s) red[t]+=red[t+s]; __syncthreads(); }
  if(t==0) y[b]=red[0];
}

// ---------------------------------------------------------------- sinkhorn + WP
__global__ void __launch_bounds__(256) k_sinkhorn(
    const float* __restrict__ Ec, const float* __restrict__ V,
    const float* __restrict__ Ws, const float* __restrict__ PrInv,
    const int* __restrict__ x, float* __restrict__ mats,
    float* __restrict__ partial){
  int idx = blockIdx.x*256 + threadIdx.x;
  int i = idx>>10, j = idx&1023;
  if(i==0) return;
  int t = threadIdx.x;
  int lane = t & 63, wv = t >> 6;
  __shared__ float sE[256][17];
  float E[16];
  {
    const float4* p = (const float4*)(Ec + (size_t)idx*16);
    float4 q0=p[0], q1=p[1], q2=p[2], q3=p[3];
    E[0]=__expf(q0.x); E[1]=__expf(q0.y); E[2]=__expf(q0.z); E[3]=__expf(q0.w);
    E[4]=__expf(q1.x); E[5]=__expf(q1.y); E[6]=__expf(q1.z); E[7]=__expf(q1.w);
    E[8]=__expf(q2.x); E[9]=__expf(q2.y); E[10]=__expf(q2.z); E[11]=__expf(q2.w);
    E[12]=__expf(q3.x);E[13]=__expf(q3.y);E[14]=__expf(q3.z); E[15]=__expf(q3.w);
  }
  float s0=0.f;
  #pragma unroll
  for(int q=0;q<16;q++) s0+=E[q];
  float is0 = frcp(s0);
  #pragma unroll
  for(int q=0;q<16;q++) E[q]*=is0;
  float av[4], bv[4];
  {
    float4 va = ((const float4*)V)[i];
    av[0]=va.x; av[1]=va.y; av[2]=va.z; av[3]=va.w;
    float4 vb = ((const float4*)V)[j];
    bv[0]=vb.x; bv[1]=vb.y; bv[2]=vb.z; bv[3]=vb.w;
  }
  for(int it=0; it<NSINK; ++it){
    #pragma unroll
    for(int r=0;r<4;r++){
      float rs = E[4*r]+E[4*r+1]+E[4*r+2]+E[4*r+3];
      float sc = av[r]*frcp(rs+1e-7f);
      E[4*r]*=sc; E[4*r+1]*=sc; E[4*r+2]*=sc; E[4*r+3]*=sc;
    }
    #pragma unroll
    for(int c=0;c<4;c++){
      float cs = E[c]+E[4+c]+E[8+c]+E[12+c];
      float sc = bv[c]*frcp(cs+1e-7f);
      E[c]*=sc; E[4+c]*=sc; E[8+c]*=sc; E[12+c]*=sc;
    }
  }
  #pragma unroll
  for(int q=0;q<16;q++) sE[t][q] = fminf(fmaxf(E[q],0.f),1.f);
  float wsij = Ws[idx];
  for(int b=0;b<32;b++){
    int xi = x[b*1024+i];
    int xj = x[b*1024+j];
    float val = sE[t][(xi<<2)+xj] * wsij * PrInv[b*1024+i] * PrInv[b*1024+j];
    if(j!=0)
      mats[(size_t)(1+b)*MSZ + (size_t)(i-1)*1024 + (j-1)] = 1e-7f - val;
    float r = val;
    r += __shfl_down(r,32); r += __shfl_down(r,16); r += __shfl_down(r,8);
    r += __shfl_down(r,4);  r += __shfl_down(r,2);  r += __shfl_down(r,1);
    if(lane==0)
      partial[((size_t)b<<14) + ((size_t)(i-1)<<4) + ((blockIdx.x&3)<<2) + wv] = r;
  }
}

// ---------------------------------------------------------------- L0 build
__global__ void k_l0(const float* __restrict__ Ws, float* __restrict__ mats){
  int r = blockIdx.x, t = threadIdx.x;
  float* orow = mats + (size_t)r*1024;
  if(r == 1023){
    float4 o = make_float4(0.f,0.f,0.f,0.f);
    if(t==255) o.w = 1.f;
    ((float4*)orow)[t] = o;
    return;
  }
  const float* wrow = Ws + (size_t)(r+1)*1024;
  float4 v = ((const float4*)wrow)[t];
  __shared__ float red[256];
  red[t] = v.x+v.y+v.z+v.w;
  __syncthreads();
  for(int s=128;s>0;s>>=1){ if(t<s) red[t]+=red[t+s]; __syncthreads(); }
  float rs = red[0];
  float o[4];
  #pragma unroll
  for(int q=0;q<4;q++){
    int c = 4*t+q;
    if(c==r)          o[q] = rs + 1e-7f;
    else if(c < 1023) o[q] = 1e-7f - wrow[c+1];
    else              o[q] = 0.f;
  }
  ((float4*)orow)[t] = make_float4(o[0],o[1],o[2],o[3]);
}

__global__ void k_patch(float* __restrict__ mats, const float* __restrict__ partial){
  int m = blockIdx.y + 1;
  int r = blockIdx.x*256 + threadIdx.x;
  float* A = mats + (size_t)m*MSZ;
  A[(size_t)r*1024 + 1023] = (r==1023) ? 1.f : 0.f;
  if(r < 1023){
    A[(size_t)1023*1024 + r] = 0.f;
    const float* pp = partial + (((size_t)(m-1))<<14) + ((size_t)r<<4);
    float s = 0.f;
    #pragma unroll
    for(int q=0;q<16;q++) s += pp[q];
    A[(size_t)r*1024 + r] = s + 1e-7f;
  }
}

// ---------------------------------------------------------- 128x128 diag LU
// STANDALONE kernel (R2/R4/R5 lesson: LU code co-compiled with MFMA kernels
// gets poisoned codegen; keep it isolated).  One block per matrix, 4 waves,
// 64KB LDS holding the 128x128 diag block.  Blocked in-place LU:
//   wave0: LU64(D11) -> L11\U11 in place
//   wave0: U12 = L11^-1 D12 (col/lane forward subst, in place)
//   wave1: L21 = D21 U11^-1 (row/lane back subst, in place)
//   all:   D22 -= L21*U12 (fp32 fma)
//   wave0: LU64(D22); logdet += both pivot sums
// Then (if inv) 256 lanes each compute ONE column of Uinv128 (t<128) or
// Linv128 (t>=128) by fully-unrolled substitution over the composed LU
// (zero-init x + full-quad reads: untouched x entries are 0, so reading the
// opposite triangle contributes nothing).  Emits split-bf16 UinvT row-major
// [n][k] and Linv row-major [n][k] (k-stride 128) — trsm B-fragment layouts.
__global__ void __launch_bounds__(256) k_diag(const float* __restrict__ mats_,
    unsigned short* __restrict__ UiH, unsigned short* __restrict__ UiL,
    unsigned short* __restrict__ LiH, unsigned short* __restrict__ LiL,
    float* __restrict__ logdet, int k, int inv){
  int m = blockIdx.x;
  const float* A = mats_ + (size_t)m*MSZ;
  int t = threadIdx.x, lane = t & 63, w = t >> 6;
  __shared__ float sm[128*128];   // 64 KB

  // load D = A[k:k+128, k:k+128]
  {
    int r = t >> 1, h = (t & 1) * 64;
    const float4* src = (const float4*)(A + (size_t)(k + r)*1024 + k + h);
    float4* dst = (float4*)&sm[r*128 + h];
    #pragma unroll
    for(int q=0;q<16;q++) dst[q] = src[q];
  }
  __syncthreads();

  float slog = 0.f;
  // ---- LU64 on D11 (wave 0)
  if(w==0){
    float row[64];
    #pragma unroll
    for(int q4=0;q4<16;q4++){
      float4 v = *(const float4*)&sm[lane*128 + 4*q4];
      row[4*q4]=v.x; row[4*q4+1]=v.y; row[4*q4+2]=v.z; row[4*q4+3]=v.w;
    }
    #pragma unroll
    for(int c=0;c<64;c++){
      float piv = __shfl(row[c], c);
      slog += logf(fabsf(piv));
      float ip = frcp(piv);
      bool below = lane > c;
      float lic = below ? row[c]*ip : 0.f;
      if(below) row[c] = lic;
      #pragma unroll
      for(int q=c+1;q<64;q++){
        float uq = __shfl(row[q], c);
        row[q] = fmaf(-lic, uq, row[q]);
      }
    }
    #pragma unroll
    for(int q=0;q<64;q++) sm[lane*128+q] = row[q];
  }
  __syncthreads();

  // ---- panel solves inside the block
  if(w==0){
    // U12 col j=lane: forward subst (unit L11).  zero-init + full quads:
    // x[c>=r] still 0, so reading U/diag there contributes nothing.
    float x[64];
    #pragma unroll
    for(int q=0;q<64;q++) x[q]=0.f;
    #pragma unroll
    for(int r=0;r<64;r++){
      float a0=0.f,a1=0.f,a2=0.f,a3=0.f;
      #pragma unroll
      for(int c=0;c<((r+3)&~3);c+=4){
        float4 u = *(const float4*)&sm[r*128+c];
        a0=fmaf(u.x,x[c],a0);   a1=fmaf(u.y,x[c+1],a1);
        a2=fmaf(u.z,x[c+2],a2); a3=fmaf(u.w,x[c+3],a3);
      }
      x[r] = sm[r*128 + 64 + lane] - ((a0+a1)+(a2+a3));
    }
    #pragma unroll
    for(int r=0;r<64;r++) sm[r*128 + 64 + lane] = x[r];
  } else if(w==1){
    // L21 row i=lane: back subst along the row against U11.
    float x[64];
    #pragma unroll
    for(int q=0;q<64;q++) x[q]=0.f;
    #pragma unroll
    for(int c=0;c<64;c++){
      float a0=0.f,a1=0.f,a2=0.f,a3=0.f;
      #pragma unroll
      for(int p=0;p<((c+3)&~3);p+=4){
        a0 = fmaf(x[p],   sm[p*128+c],     a0);
        a1 = fmaf(x[p+1], sm[(p+1)*128+c], a1);
        a2 = fmaf(x[p+2], sm[(p+2)*128+c], a2);
        a3 = fmaf(x[p+3], sm[(p+3)*128+c], a3);
      }
      float d = sm[(64+lane)*128 + c];
      x[c] = (d - ((a0+a1)+(a2+a3))) * frcp(sm[c*128+c]);
    }
    #pragma unroll
    for(int c=0;c<64;c++) sm[(64+lane)*128 + c] = x[c];
  }
  __syncthreads();

  // ---- Schur: D22 -= L21*U12   (lane = col j, wave = row strip)
  {
    int j = lane;
    #pragma unroll
    for(int ii=0; ii<16; ii++){
      int i = w*16 + ii;
      float acc2 = sm[(64+i)*128 + 64 + j];
      #pragma unroll
      for(int p=0;p<64;p+=4){
        float4 l4 = *(const float4*)&sm[(64+i)*128 + p];   // uniform
        acc2 = fmaf(-l4.x, sm[(p  )*128 + 64 + j], acc2);
        acc2 = fmaf(-l4.y, sm[(p+1)*128 + 64 + j], acc2);
        acc2 = fmaf(-l4.z, sm[(p+2)*128 + 64 + j], acc2);
        acc2 = fmaf(-l4.w, sm[(p+3)*128 + 64 + j], acc2);
      }
      sm[(64+i)*128 + 64 + j] = acc2;
    }
  }
  __syncthreads();

  // ---- LU64 on updated D22 (wave 0)
  if(w==0){
    float row[64];
    #pragma unroll
    for(int q4=0;q4<16;q4++){
      float4 v = *(const float4*)&sm[(64+lane)*128 + 64 + 4*q4];
      row[4*q4]=v.x; row[4*q4+1]=v.y; row[4*q4+2]=v.z; row[4*q4+3]=v.w;
    }
    #pragma unroll
    for(int c=0;c<64;c++){
      float piv = __shfl(row[c], c);
      slog += logf(fabsf(piv));
      float ip = frcp(piv);
      bool below = lane > c;
      float lic = below ? row[c]*ip : 0.f;
      if(below) row[c] = lic;
      #pragma unroll
      for(int q=c+1;q<64;q++){
        float uq = __shfl(row[q], c);
        row[q] = fmaf(-lic, uq, row[q]);
      }
    }
    #pragma unroll
    for(int q=0;q<64;q++) sm[(64+lane)*128 + 64 + q] = row[q];
    if(lane==0){ if(k==0) logdet[m]=slog; else logdet[m]+=slog; }
  }
  __syncthreads();
  if(!inv) return;

  // ---- full 128-column inverses by substitution over the composed LU
  int col = t & 127;
  if(t < 128){
    // Uinv column `col` (back subst, descending r; x fills top-down so
    // quad overshoot into c<=r reads x==0)
    float x[128];
    #pragma unroll
    for(int q=0;q<128;q++) x[q]=0.f;
    #pragma unroll
    for(int r=127;r>=0;r--){
      float a0=0.f,a1=0.f,a2=0.f,a3=0.f;
      #pragma unroll
      for(int c=(r+1)&~3; c<128; c+=4){
        float4 u = *(const float4*)&sm[r*128+c];
        a0=fmaf(u.x,x[c],a0);   a1=fmaf(u.y,x[c+1],a1);
        a2=fmaf(u.z,x[c+2],a2); a3=fmaf(u.w,x[c+3],a3);
      }
      float ip = frcp(sm[r*128+r]);
      float sv = (a0+a1)+(a2+a3);
      x[r] = (r==col) ? ip : -sv*ip;
    }
    // lane holds UinvT row `col` -> split bf16 contiguous
    unsigned short* ph = UiH + (size_t)m*16384 + (size_t)col*128;
    unsigned short* pl = UiL + (size_t)m*16384 + (size_t)col*128;
    #pragma unroll
    for(int p8=0;p8<16;p8++){
      u16x8 h8, l8;
      #pragma unroll
      for(int e=0;e<8;e++){
        float v = x[p8*8+e];
        unsigned short h = bf16rn(v);
        h8[e]=h; l8[e]=bf16rn(v - bf2f(h));
      }
      ((u16x8*)ph)[p8]=h8; ((u16x8*)pl)[p8]=l8;
    }
    __syncthreads();      // pair with Linv waves below
    __syncthreads();
  } else {
    // Linv column `col` (forward subst, unit diag)
    float x[128];
    #pragma unroll
    for(int q=0;q<128;q++) x[q]=0.f;
    #pragma unroll
    for(int r=0;r<128;r++){
      float a0=0.f,a1=0.f,a2=0.f,a3=0.f;
      #pragma unroll
      for(int c=0; c<((r+3)&~3); c+=4){
        float4 u = *(const float4*)&sm[r*128+c];
        a0=fmaf(u.x,x[c],a0);   a1=fmaf(u.y,x[c+1],a1);
        a2=fmaf(u.z,x[c+2],a2); a3=fmaf(u.w,x[c+3],a3);
      }
      x[r] = (r==col) ? 1.f : -((a0+a1)+(a2+a3));
    }
    __syncthreads();      // Uinv waves done reading sm
    #pragma unroll
    for(int r=0;r<128;r++) sm[r*128 + col] = x[r];   // transpose via LDS
    __syncthreads();
    // emit Linv row-major row `col`
    unsigned short* ph = LiH + (size_t)m*16384 + (size_t)col*128;
    unsigned short* pl = LiL + (size_t)m*16384 + (size_t)col*128;
    #pragma unroll
    for(int p8=0;p8<16;p8++){
      float4 u0 = *(const float4*)&sm[col*128 + p8*8];
      float4 u1 = *(const float4*)&sm[col*128 + p8*8 + 4];
      float v[8] = {u0.x,u0.y,u0.z,u0.w,u1.x,u1.y,u1.z,u1.w};
      u16x8 h8, l8;
      #pragma unroll
      for(int e=0;e<8;e++){
        unsigned short h = bf16rn(v[e]);
        h8[e]=h; l8[e]=bf16rn(v[e] - bf2f(h));
      }
      ((u16x8*)ph)[p8]=h8; ((u16x8*)pl)[p8]=l8;
    }
  }
}

// ---------------------------------------------------------------- MFMA trsm
// K=128.  L21 = A21 * Uinv128 (blockIdx.x < nb), U12^T = A12^T * Linv128^T.
// Wave: 32 rows x 128 out cols, 8 kc chunks x 4 ct x 3 = 96 MFMAs.
// rem % 128 == 0 always -> no bounds checks.
__global__ void __launch_bounds__(256) k_trsm(const float* __restrict__ mats_,
    const unsigned short* __restrict__ UiH, const unsigned short* __restrict__ UiL,
    const unsigned short* __restrict__ LiH, const unsigned short* __restrict__ LiL,
    unsigned short* __restrict__ Ah, unsigned short* __restrict__ Al,
    unsigned short* __restrict__ Bh, unsigned short* __restrict__ Bl,
    int k){
  int m = blockIdx.y;
  const float* A = mats_ + (size_t)m*MSZ;
  int rem = 1024 - (k+128);
  int nb = rem >> 7;
  bool aside = (int)blockIdx.x < nb;
  int t = threadIdx.x, lane = t&63;
  int r32 = lane&31, hi = lane>>5, wv = t>>6;
  int tile0 = (aside ? (int)blockIdx.x : (int)blockIdx.x - nb)*128 + wv*32;
  int rel  = tile0 + r32;

  const unsigned short* IH = (aside ? UiH : LiH) + (size_t)m*16384;
  const unsigned short* IL = (aside ? UiL : LiL) + (size_t)m*16384;

  f32x16 acc[4];
  #pragma unroll
  for(int ct=0;ct<4;ct++)
    #pragma unroll
    for(int q=0;q<16;q++) acc[ct][q]=0.f;

  #pragma unroll
  for(int kc=0;kc<8;kc++){
    float v[8];
    if(aside){
      const float* src = A + (size_t)(k+128+rel)*1024 + k + kc*16 + hi*8;
      float4 u0 = ((const float4*)src)[0];
      float4 u1 = ((const float4*)src)[1];
      v[0]=u0.x; v[1]=u0.y; v[2]=u0.z; v[3]=u0.w;
      v[4]=u1.x; v[5]=u1.y; v[6]=u1.z; v[7]=u1.w;
    } else {
      const float* src = A + (size_t)(k + kc*16 + hi*8)*1024 + (k+128+rel);
      #pragma unroll
      for(int e=0;e<8;e++) v[e] = src[(size_t)e*1024];
    }
    bfrag ah, al;
    #pragma unroll
    for(int e=0;e<8;e++){
      unsigned short h = bf16rn(v[e]);
      ah[e] = (short)h;
      al[e] = (short)bf16rn(v[e] - bf2f(h));
    }
    #pragma unroll
    for(int ct=0;ct<4;ct++){
      bfrag bh = *(const bfrag*)(IH + (size_t)(ct*32+r32)*128 + kc*16 + hi*8);
      bfrag bl = *(const bfrag*)(IL + (size_t)(ct*32+r32)*128 + kc*16 + hi*8);
      acc[ct] = __builtin_amdgcn_mfma_f32_32x32x16_bf16(ah, bh, acc[ct], 0,0,0);
      acc[ct] = __builtin_amdgcn_mfma_f32_32x32x16_bf16(ah, bl, acc[ct], 0,0,0);
      acc[ct] = __builtin_amdgcn_mfma_f32_32x32x16_bf16(al, bh, acc[ct], 0,0,0);
    }
  }

  unsigned short* PH = (aside ? Ah : Bh) + (size_t)m*PANSZ;
  unsigned short* PL = (aside ? Al : Bl) + (size_t)m*PANSZ;
  #pragma unroll
  for(int ct=0;ct<4;ct++){
    #pragma unroll
    for(int reg=0;reg<16;reg++){
      int crow = (reg&3) + ((reg>>2)<<3) + (hi<<2);
      int r = tile0 + crow;
      float v = acc[ct][reg];
      unsigned short h = bf16rn(v);
      size_t off = (size_t)r*128 + ct*32 + r32;
      PH[off] = h;
      PL[off] = bf16rn(v - bf2f(h));
    }
  }
}

// ------------------------------------------------------- MFMA split-bf16 Schur
// A22 -= L21 * U12, K=128 in 4 staged 32-chunks.  128x128 C tile, 4 waves.
// rem % 128 == 0 -> no bounds checks.
__global__ void __launch_bounds__(256) k_gemm(float* __restrict__ mats,
    const unsigned short* __restrict__ Ah, const unsigned short* __restrict__ Al,
    const unsigned short* __restrict__ Bh, const unsigned short* __restrict__ Bl,
    int k){
  int m = blockIdx.z;
  float* A = mats + (size_t)m*MSZ;
  int i0rel = blockIdx.y*128;
  int j0rel = blockIdx.x*128;
  __shared__ unsigned short As[2][4096];   // [hi/lo][row*32 + swz(koct)*8]
  __shared__ unsigned short Bs[2][4096];
  int t = threadIdx.x;
  int lane = t & 63, wvi = t >> 6;
  int wr = wvi >> 1, wc = wvi & 1;

  const unsigned short* pAh = Ah + (size_t)m*PANSZ;
  const unsigned short* pAl = Al + (size_t)m*PANSZ;
  const unsigned short* pBh = Bh + (size_t)m*PANSZ;
  const unsigned short* pBl = Bl + (size_t)m*PANSZ;

  int ldsOff[2];
  size_t offA[2], offB[2];
  #pragma unroll
  for(int p=0;p<2;p++){
    int c = t + 256*p;
    int row = c>>2, koct = c&3;
    ldsOff[p] = row*32 + ((koct ^ ((row>>1)&3))<<3);
    offA[p] = (size_t)(i0rel+row)*128 + koct*8;
    offB[p] = (size_t)(j0rel+row)*128 + koct*8;
  }

  // stage 0 -> LDS
  #pragma unroll
  for(int p=0;p<2;p++){
    u16x8 a0 = *(const u16x8*)(pAh + offA[p]);
    u16x8 a1 = *(const u16x8*)(pAl + offA[p]);
    u16x8 b0 = *(const u16x8*)(pBh + offB[p]);
    u16x8 b1 = *(const u16x8*)(pBl + offB[p]);
    *(u16x8*)&As[0][ldsOff[p]] = a0;
    *(u16x8*)&As[1][ldsOff[p]] = a1;
    *(u16x8*)&Bs[0][ldsOff[p]] = b0;
    *(u16x8*)&Bs[1][ldsOff[p]] = b1;
  }
  // stage 1 -> regs
  u16x8 p1[8];
  #pragma unroll
  for(int p=0;p<2;p++){
    p1[4*p+0] = *(const u16x8*)(pAh + offA[p] + 32);
    p1[4*p+1] = *(const u16x8*)(pAl + offA[p] + 32);
    p1[4*p+2] = *(const u16x8*)(pBh + offB[p] + 32);
    p1[4*p+3] = *(const u16x8*)(pBl + offB[p] + 32);
  }
  __syncthreads();

  f32x16 acc[2][2];
  #pragma unroll
  for(int rt=0;rt<2;rt++)
    #pragma unroll
    for(int ct=0;ct<2;ct++)
      #pragma unroll
      for(int q=0;q<16;q++) acc[rt][ct][q] = 0.f;

  int kgrp = lane >> 5;
  #pragma unroll
  for(int st=0; st<4; st++){
    #pragma unroll
    for(int kc=0;kc<2;kc++){
      int koct = kc*2 + kgrp;
      bfrag ah[2], al[2], bh[2], bl[2];
      #pragma unroll
      for(int rt=0;rt<2;rt++){
        int row = wr*64 + rt*32 + (lane&31);
        int ad = row*32 + ((koct ^ ((row>>1)&3))<<3);
        ah[rt] = *(const bfrag*)&As[0][ad];
        al[rt] = *(const bfrag*)&As[1][ad];
      }
      #pragma unroll
      for(int ct=0;ct<2;ct++){
        int col = wc*64 + ct*32 + (lane&31);
        int ad = col*32 + ((koct ^ ((col>>1)&3))<<3);
        bh[ct] = *(const bfrag*)&Bs[0][ad];
        bl[ct] = *(const bfrag*)&Bs[1][ad];
      }
      #pragma unroll
      for(int rt=0;rt<2;rt++)
        #pragma unroll
        for(int ct=0;ct<2;ct++){
          acc[rt][ct] = __builtin_amdgcn_mfma_f32_32x32x16_bf16(ah[rt], bh[ct], acc[rt][ct], 0,0,0);
          acc[rt][ct] = __builtin_amdgcn_mfma_f32_32x32x16_bf16(ah[rt], bl[ct], acc[rt][ct], 0,0,0);
          acc[rt][ct] = __builtin_amdgcn_mfma_f32_32x32x16_bf16(al[rt], bh[ct], acc[rt][ct], 0,0,0);
        }
    }
    if(st<3){
      __syncthreads();   // stage-st reads done
      #pragma unroll
      for(int p=0;p<2;p++){
        *(u16x8*)&As[0][ldsOff[p]] = p1[4*p+0];
        *(u16x8*)&As[1][ldsOff[p]] = p1[4*p+1];
        *(u16x8*)&Bs[0][ldsOff[p]] = p1[4*p+2];
        *(u16x8*)&Bs[1][ldsOff[p]] = p1[4*p+3];
      }
      if(st<2){
        #pragma unroll
        for(int p=0;p<2;p++){
          p1[4*p+0] = *(const u16x8*)(pAh + offA[p] + (st+2)*32);
          p1[4*p+1] = *(const u16x8*)(pAl + offA[p] + (st+2)*32);
          p1[4*p+2] = *(const u16x8*)(pBh + offB[p] + (st+2)*32);
          p1[4*p+3] = *(const u16x8*)(pBl + offB[p] + (st+2)*32);
        }
      }
      __syncthreads();
    }
  }

  // C RMW epilogue (C/D layout: col=lane&31, row=(reg&3)+8*(reg>>2)+4*(lane>>5))
  int r0 = k + 128;
  #pragma unroll
  for(int rt=0;rt<2;rt++){
    int rowblk = i0rel + wr*64 + rt*32;
    #pragma unroll
    for(int ct=0;ct<2;ct++){
      int colblk = j0rel + wc*64 + ct*32;
      int col = r0 + colblk + (lane&31);
      int rbase = r0 + rowblk + ((lane>>5)<<2);
      #pragma unroll
      for(int reg=0;reg<16;reg++){
        int row = rbase + (reg&3) + ((reg>>2)<<3);
        float* pc = A + (size_t)row*1024 + col;
        *pc -= acc[rt][ct][reg];
      }
    }
  }
}

__global__ void k_final(const float* __restrict__ y, const float* __restrict__ logdet,
                        float* __restrict__ out){
  int b = threadIdx.x;
  if(b<32) out[b] = y[b] + logdet[1+b] - logdet[0];
}

// ---------------------------------------------------------------- launch
extern "C" void kernel_launch(void* const* d_in, const int* in_sizes, int n_in,
                              void* d_out, int out_size, void* d_ws, size_t ws_size,
                              hipStream_t stream){
  (void)in_sizes; (void)n_in; (void)out_size; (void)ws_size;
  const int*   x  = (const int*)d_in[0];
  const float* W  = (const float*)d_in[1];
  const float* Vc = (const float*)d_in[2];
  const float* Ec = (const float*)d_in[3];
  float* out = (float*)d_out;

  char* p = (char*)d_ws;
  auto alloc = [&](size_t bytes)->char*{ char* r = p; p += (bytes+255)&~(size_t)255; return r; };
  float* mats   = (float*)alloc((size_t)NMAT*MSZ*4);              // 138.4 MB
  float* Ws     = (float*)alloc(1048576ull*4);
  unsigned short* Ah = (unsigned short*)alloc((size_t)NMAT*PANSZ*2);
  unsigned short* Al = (unsigned short*)alloc((size_t)NMAT*PANSZ*2);
  unsigned short* Bh = (unsigned short*)alloc((size_t)NMAT*PANSZ*2);
  unsigned short* Bl = (unsigned short*)alloc((size_t)NMAT*PANSZ*2);
  unsigned short* UiH = (unsigned short*)alloc((size_t)NMAT*16384*2);  // 1 MB each
  unsigned short* UiL = (unsigned short*)alloc((size_t)NMAT*16384*2);
  unsigned short* LiH = (unsigned short*)alloc((size_t)NMAT*16384*2);
  unsigned short* LiL = (unsigned short*)alloc((size_t)NMAT*16384*2);
  float* V      = (float*)alloc(4096*4);
  float* PrInv  = (float*)alloc(32768*4);
  float* partial= (float*)alloc((size_t)32*16384*4);              // 2 MB
  float* y      = (float*)alloc(256);
  float* logdet = (float*)alloc(256);

  k_misc<<<4100,256,0,stream>>>(Vc, V, W, Ws);
  k_pr_y<<<32,256,0,stream>>>(V, x, PrInv, y);
  k_sinkhorn<<<4096,256,0,stream>>>(Ec, V, Ws, PrInv, x, mats, partial);
  k_l0<<<1024,256,0,stream>>>(Ws, mats);
  k_patch<<<dim3(4,32),256,0,stream>>>(mats, partial);

  k_diag<<<NMAT,256,0,stream>>>(mats, UiH,UiL,LiH,LiL, logdet, 0, 1);
  for(int s=0;s<7;s++){
    int k = 128*s;
    int rem = 1024 - (k+128);
    int nb = rem/128;
    k_trsm<<<dim3(2*nb,NMAT),256,0,stream>>>(mats, UiH,UiL,LiH,LiL, Ah,Al,Bh,Bl, k);
    k_gemm<<<dim3(nb,nb,NMAT),256,0,stream>>>(mats, Ah,Al,Bh,Bl, k);
    k_diag<<<NMAT,256,0,stream>>>(mats, UiH,UiL,LiH,LiL, logdet, k+128, (s<6)?1:0);
  }
  k_final<<<1,32,0,stream>>>(y, logdet, out);
}

// Round 7
// 1553.343 us; speedup vs baseline: 1.6393x; 1.0621x over previous
//
#include <hip/hip_runtime.h>
#include <math.h>

#define MSZ    1048576ull  // 1024*1024 elements per matrix slot
#define NMAT   33          // matrix 0 = L0, matrices 1..32 = per-batch L
#define PANSZ  114688      // 896*128 shorts per matrix per panel plane
#define NSINK  14

__device__ __forceinline__ float frcp(float x){ return __builtin_amdgcn_rcpf(x); }

typedef __attribute__((ext_vector_type(8)))  short  bfrag;   // 8 x bf16 (4 VGPR)
typedef __attribute__((ext_vector_type(8)))  unsigned short u16x8;
typedef __attribute__((ext_vector_type(16))) float  f32x16;  // 32x32 acc

__device__ __forceinline__ unsigned short bf16rn(float x){
  unsigned u = __float_as_uint(x);
  unsigned r = u + 0x7fffu + ((u>>16)&1u);
  return (unsigned short)(r>>16);
}
__device__ __forceinline__ float bf2f(unsigned short h){
  return __uint_as_float(((unsigned)h)<<16);
}

// ---------------------------------------------------------------- setup
__global__ void k_misc(const float* __restrict__ Vc, float* __restrict__ V,
                       const float* __restrict__ W, float* __restrict__ Ws){
  int t = threadIdx.x;
  if(blockIdx.x < 4){
    int i = blockIdx.x*256 + t;
    float4 v = ((const float4*)Vc)[i];
    float mx = fmaxf(fmaxf(v.x,v.y), fmaxf(v.z,v.w));
    float e0=__expf(v.x-mx), e1=__expf(v.y-mx), e2=__expf(v.z-mx), e3=__expf(v.w-mx);
    float is = 1.f/(e0+e1+e2+e3);
    ((float4*)V)[i] = make_float4(e0*is, e1*is, e2*is, e3*is);
  } else {
    int idx = (blockIdx.x-4)*256 + t;
    int i = idx>>10, j = idx&1023;
    float v = 0.f;
    if(i != j){
      float w = (i>j) ? W[i*1024+j] : W[j*1024+i];
      v = 1.f/(1.f+__expf(-w));
    }
    Ws[idx]=v;
  }
}

__global__ void k_pr_y(const float* __restrict__ V, const int* __restrict__ x,
                       float* __restrict__ PrInv, float* __restrict__ y){
  int b = blockIdx.x, t = threadIdx.x;
  __shared__ float red[256];
  float acc = 0.f;
  for(int i=t; i<1024; i+=256){
    int xv = x[b*1024+i];
    float pr = V[i*4+xv];
    PrInv[b*1024+i] = 1.f/pr;
    acc += logf(pr + 1e-7f);
  }
  red[t]=acc; __syncthreads();
  for(int s=128;s>0;s>>=1){ if(t<s) red[t]+=red[t+s]; __syncthreads(); }
  if(t==0) y[b]=red[0];
}

// ---------------------------------------------------------------- sinkhorn + WP
__global__ void __launch_bounds__(256) k_sinkhorn(
    const float* __restrict__ Ec, const float* __restrict__ V,
    const float* __restrict__ Ws, const float* __restrict__ PrInv,
    const int* __restrict__ x, float* __restrict__ mats,
    float* __restrict__ partial){
  int idx = blockIdx.x*256 + threadIdx.x;
  int i = idx>>10, j = idx&1023;
  if(i==0) return;
  int t = threadIdx.x;
  int lane = t & 63, wv = t >> 6;
  __shared__ float sE[256][17];
  float E[16];
  {
    const float4* p = (const float4*)(Ec + (size_t)idx*16);
    float4 q0=p[0], q1=p[1], q2=p[2], q3=p[3];
    E[0]=__expf(q0.x); E[1]=__expf(q0.y); E[2]=__expf(q0.z); E[3]=__expf(q0.w);
    E[4]=__expf(q1.x); E[5]=__expf(q1.y); E[6]=__expf(q1.z); E[7]=__expf(q1.w);
    E[8]=__expf(q2.x); E[9]=__expf(q2.y); E[10]=__expf(q2.z); E[11]=__expf(q2.w);
    E[12]=__expf(q3.x);E[13]=__expf(q3.y);E[14]=__expf(q3.z); E[15]=__expf(q3.w);
  }
  float s0=0.f;
  #pragma unroll
  for(int q=0;q<16;q++) s0+=E[q];
  float is0 = frcp(s0);
  #pragma unroll
  for(int q=0;q<16;q++) E[q]*=is0;
  float av[4], bv[4];
  {
    float4 va = ((const float4*)V)[i];
    av[0]=va.x; av[1]=va.y; av[2]=va.z; av[3]=va.w;
    float4 vb = ((const float4*)V)[j];
    bv[0]=vb.x; bv[1]=vb.y; bv[2]=vb.z; bv[3]=vb.w;
  }
  for(int it=0; it<NSINK; ++it){
    #pragma unroll
    for(int r=0;r<4;r++){
      float rs = E[4*r]+E[4*r+1]+E[4*r+2]+E[4*r+3];
      float sc = av[r]*frcp(rs+1e-7f);
      E[4*r]*=sc; E[4*r+1]*=sc; E[4*r+2]*=sc; E[4*r+3]*=sc;
    }
    #pragma unroll
    for(int c=0;c<4;c++){
      float cs = E[c]+E[4+c]+E[8+c]+E[12+c];
      float sc = bv[c]*frcp(cs+1e-7f);
      E[c]*=sc; E[4+c]*=sc; E[8+c]*=sc; E[12+c]*=sc;
    }
  }
  #pragma unroll
  for(int q=0;q<16;q++) sE[t][q] = fminf(fmaxf(E[q],0.f),1.f);
  float wsij = Ws[idx];
  for(int b=0;b<32;b++){
    int xi = x[b*1024+i];
    int xj = x[b*1024+j];
    float val = sE[t][(xi<<2)+xj] * wsij * PrInv[b*1024+i] * PrInv[b*1024+j];
    if(j!=0)
      mats[(size_t)(1+b)*MSZ + (size_t)(i-1)*1024 + (j-1)] = 1e-7f - val;
    float r = val;
    r += __shfl_down(r,32); r += __shfl_down(r,16); r += __shfl_down(r,8);
    r += __shfl_down(r,4);  r += __shfl_down(r,2);  r += __shfl_down(r,1);
    if(lane==0)
      partial[((size_t)b<<14) + ((size_t)(i-1)<<4) + ((blockIdx.x&3)<<2) + wv] = r;
  }
}

// ---------------------------------------------------------------- L0 build
__global__ void k_l0(const float* __restrict__ Ws, float* __restrict__ mats){
  int r = blockIdx.x, t = threadIdx.x;
  float* orow = mats + (size_t)r*1024;
  if(r == 1023){
    float4 o = make_float4(0.f,0.f,0.f,0.f);
    if(t==255) o.w = 1.f;
    ((float4*)orow)[t] = o;
    return;
  }
  const float* wrow = Ws + (size_t)(r+1)*1024;
  float4 v = ((const float4*)wrow)[t];
  __shared__ float red[256];
  red[t] = v.x+v.y+v.z+v.w;
  __syncthreads();
  for(int s=128;s>0;s>>=1){ if(t<s) red[t]+=red[t+s]; __syncthreads(); }
  float rs = red[0];
  float o[4];
  #pragma unroll
  for(int q=0;q<4;q++){
    int c = 4*t+q;
    if(c==r)          o[q] = rs + 1e-7f;
    else if(c < 1023) o[q] = 1e-7f - wrow[c+1];
    else              o[q] = 0.f;
  }
  ((float4*)orow)[t] = make_float4(o[0],o[1],o[2],o[3]);
}

__global__ void k_patch(float* __restrict__ mats, const float* __restrict__ partial){
  int m = blockIdx.y + 1;
  int r = blockIdx.x*256 + threadIdx.x;
  float* A = mats + (size_t)m*MSZ;
  A[(size_t)r*1024 + 1023] = (r==1023) ? 1.f : 0.f;
  if(r < 1023){
    A[(size_t)1023*1024 + r] = 0.f;
    const float* pp = partial + (((size_t)(m-1))<<14) + ((size_t)r<<4);
    float s = 0.f;
    #pragma unroll
    for(int q=0;q<16;q++) s += pp[q];
    A[(size_t)r*1024 + r] = s + 1e-7f;
  }
}

// ---------------------------------------------------------- 128x128 diag LU
// R6 structure, but ALL substitutions in SAXPY (outer-product) order: the LDS
// loads (columns of U / rows of L, uniform broadcast) are independent of the
// recurrence, so the serial chain is VALU-only and the loop is issue-bound
// (R6's dot-form put every ds_read on the dependent chain: 144us).
// The L-inverse is computed ROW-wise (lane n solves x^T L = e_n^T), so both
// inverses emit split-bf16 straight from registers — no transpose buffers.
__global__ void __launch_bounds__(256) k_diag(const float* __restrict__ mats_,
    unsigned short* __restrict__ UiH, unsigned short* __restrict__ UiL,
    unsigned short* __restrict__ LiH, unsigned short* __restrict__ LiL,
    float* __restrict__ logdet, int k, int inv){
  int m = blockIdx.x;
  const float* A = mats_ + (size_t)m*MSZ;
  int t = threadIdx.x, lane = t & 63, w = t >> 6;
  __shared__ float sm[128*128];   // 64 KB

  // load D = A[k:k+128, k:k+128]
  {
    int r = t >> 1, h = (t & 1) * 64;
    const float4* src = (const float4*)(A + (size_t)(k + r)*1024 + k + h);
    float4* dst = (float4*)&sm[r*128 + h];
    #pragma unroll
    for(int q=0;q<16;q++) dst[q] = src[q];
  }
  __syncthreads();

  float slog = 0.f;
  // ---- LU64 on D11 (wave 0, shuffle form)
  if(w==0){
    float row[64];
    #pragma unroll
    for(int q4=0;q4<16;q4++){
      float4 v = *(const float4*)&sm[lane*128 + 4*q4];
      row[4*q4]=v.x; row[4*q4+1]=v.y; row[4*q4+2]=v.z; row[4*q4+3]=v.w;
    }
    #pragma unroll
    for(int c=0;c<64;c++){
      float piv = __shfl(row[c], c);
      slog += logf(fabsf(piv));
      float ip = frcp(piv);
      bool below = lane > c;
      float lic = below ? row[c]*ip : 0.f;
      if(below) row[c] = lic;
      #pragma unroll
      for(int q=c+1;q<64;q++){
        float uq = __shfl(row[q], c);
        row[q] = fmaf(-lic, uq, row[q]);
      }
    }
    #pragma unroll
    for(int q=0;q<64;q++) sm[lane*128+q] = row[q];
  }
  __syncthreads();

  // ---- panel solves, saxpy form
  if(w==0){
    // U12 = L11^-1 D12: lane = col j, in place.  Distribution reads column r
    // of L11 (uniform broadcast) — independent of the x-chain.
    float s[64];
    #pragma unroll
    for(int q=0;q<64;q++) s[q]=0.f;
    #pragma unroll
    for(int r=0;r<64;r++){
      float xr = sm[r*128 + 64 + lane] - s[r];
      sm[r*128 + 64 + lane] = xr;
      #pragma unroll
      for(int c=r+1;c<64;c++)
        s[c] = fmaf(sm[c*128 + r], xr, s[c]);
    }
  } else if(w==1){
    // L21 = D21 * U11^-1: lane = row i (staged in regs).  Distribution reads
    // row c of U11 right of diag (uniform broadcast).
    float d[64], s[64];
    {
      const float4* src4 = (const float4*)&sm[(64+lane)*128];
      #pragma unroll
      for(int q=0;q<16;q++){
        float4 v=src4[q];
        d[4*q]=v.x; d[4*q+1]=v.y; d[4*q+2]=v.z; d[4*q+3]=v.w;
      }
    }
    #pragma unroll
    for(int q=0;q<64;q++) s[q]=0.f;
    #pragma unroll
    for(int c=0;c<64;c++){
      float xc = (d[c] - s[c]) * frcp(sm[c*128+c]);
      d[c] = xc;
      #pragma unroll
      for(int q=c+1;q<64;q++)
        s[q] = fmaf(sm[c*128+q], xc, s[q]);
    }
    {
      float4* dst4 = (float4*)&sm[(64+lane)*128];
      #pragma unroll
      for(int q=0;q<16;q++)
        dst4[q] = make_float4(d[4*q],d[4*q+1],d[4*q+2],d[4*q+3]);
    }
  }
  __syncthreads();

  // ---- Schur: D22 -= L21*U12   (lane = col j, wave = row strip)
  {
    int j = lane;
    #pragma unroll
    for(int ii=0; ii<16; ii++){
      int i = w*16 + ii;
      float acc2 = sm[(64+i)*128 + 64 + j];
      #pragma unroll
      for(int p=0;p<64;p+=4){
        float4 l4 = *(const float4*)&sm[(64+i)*128 + p];   // uniform
        acc2 = fmaf(-l4.x, sm[(p  )*128 + 64 + j], acc2);
        acc2 = fmaf(-l4.y, sm[(p+1)*128 + 64 + j], acc2);
        acc2 = fmaf(-l4.z, sm[(p+2)*128 + 64 + j], acc2);
        acc2 = fmaf(-l4.w, sm[(p+3)*128 + 64 + j], acc2);
      }
      sm[(64+i)*128 + 64 + j] = acc2;
    }
  }
  __syncthreads();

  // ---- LU64 on updated D22 (wave 0)
  if(w==0){
    float row[64];
    #pragma unroll
    for(int q4=0;q4<16;q4++){
      float4 v = *(const float4*)&sm[(64+lane)*128 + 64 + 4*q4];
      row[4*q4]=v.x; row[4*q4+1]=v.y; row[4*q4+2]=v.z; row[4*q4+3]=v.w;
    }
    #pragma unroll
    for(int c=0;c<64;c++){
      float piv = __shfl(row[c], c);
      slog += logf(fabsf(piv));
      float ip = frcp(piv);
      bool below = lane > c;
      float lic = below ? row[c]*ip : 0.f;
      if(below) row[c] = lic;
      #pragma unroll
      for(int q=c+1;q<64;q++){
        float uq = __shfl(row[q], c);
        row[q] = fmaf(-lic, uq, row[q]);
      }
    }
    #pragma unroll
    for(int q=0;q<64;q++) sm[(64+lane)*128 + 64 + q] = row[q];
    if(lane==0){ if(k==0) logdet[m]=slog; else logdet[m]+=slog; }
  }
  __syncthreads();
  if(!inv) return;

  // ---- full 128 inverses, saxpy order, emit-on-the-fly from registers.
  if(t < 128){
    // Uinv column j (waves 0-1): U x = e_j, r descending.
    // x[r] = Uinv[r][j]; emission UiH[j*128 + r] in groups of 8.
    int j = t;
    float s[128];
    #pragma unroll
    for(int q=0;q<128;q++) s[q]=0.f;
    unsigned short* ph = UiH + (size_t)m*16384 + (size_t)j*128;
    unsigned short* pl = UiL + (size_t)m*16384 + (size_t)j*128;
    u16x8 H, L;
    #pragma unroll
    for(int r=127;r>=0;r--){
      float xr = (((r==j)?1.f:0.f) - s[r]) * frcp(sm[r*128+r]);
      unsigned short h = bf16rn(xr);
      H[r&7] = h; L[r&7] = bf16rn(xr - bf2f(h));
      if((r&7)==0){ ((u16x8*)ph)[r>>3] = H; ((u16x8*)pl)[r>>3] = L; }
      #pragma unroll
      for(int c=0;c<r;c++)                       // column r of U (uniform)
        s[c] = fmaf(sm[c*128+r], xr, s[c]);
    }
  } else {
    // Linv ROW n (waves 2-3): x^T L = e_n^T, c descending.
    // x[c] = Linv[n][c]; distribution reads row c of L LEFT of diag —
    // contiguous -> quad loads (overshoot into q>=c only pollutes dead s).
    int n = t - 128;
    float s[128];
    #pragma unroll
    for(int q=0;q<128;q++) s[q]=0.f;
    unsigned short* ph = LiH + (size_t)m*16384 + (size_t)n*128;
    unsigned short* pl = LiL + (size_t)m*16384 + (size_t)n*128;
    u16x8 H, L;
    #pragma unroll
    for(int c=127;c>=0;c--){
      float xc = ((c==n)?1.f:0.f) - s[c];        // unit diag
      unsigned short h = bf16rn(xc);
      H[c&7] = h; L[c&7] = bf16rn(xc - bf2f(h));
      if((c&7)==0){ ((u16x8*)ph)[c>>3] = H; ((u16x8*)pl)[c>>3] = L; }
      #pragma unroll
      for(int q4=0; 4*q4<c; q4++){
        float4 l4 = *(const float4*)&sm[c*128 + 4*q4];   // uniform
        s[4*q4  ] = fmaf(l4.x, xc, s[4*q4  ]);
        s[4*q4+1] = fmaf(l4.y, xc, s[4*q4+1]);
        s[4*q4+2] = fmaf(l4.z, xc, s[4*q4+2]);
        s[4*q4+3] = fmaf(l4.w, xc, s[4*q4+3]);
      }
    }
  }
}

// ---------------------------------------------------------------- MFMA trsm
// K=128.  L21 = A21 * Uinv128 (blockIdx.x < nb), U12^T = A12^T * Linv128^T.
__global__ void __launch_bounds__(256) k_trsm(const float* __restrict__ mats_,
    const unsigned short* __restrict__ UiH, const unsigned short* __restrict__ UiL,
    const unsigned short* __restrict__ LiH, const unsigned short* __restrict__ LiL,
    unsigned short* __restrict__ Ah, unsigned short* __restrict__ Al,
    unsigned short* __restrict__ Bh, unsigned short* __restrict__ Bl,
    int k){
  int m = blockIdx.y;
  const float* A = mats_ + (size_t)m*MSZ;
  int rem = 1024 - (k+128);
  int nb = rem >> 7;
  bool aside = (int)blockIdx.x < nb;
  int t = threadIdx.x, lane = t&63;
  int r32 = lane&31, hi = lane>>5, wv = t>>6;
  int tile0 = (aside ? (int)blockIdx.x : (int)blockIdx.x - nb)*128 + wv*32;
  int rel  = tile0 + r32;

  const unsigned short* IH = (aside ? UiH : LiH) + (size_t)m*16384;
  const unsigned short* IL = (aside ? UiL : LiL) + (size_t)m*16384;

  f32x16 acc[4];
  #pragma unroll
  for(int ct=0;ct<4;ct++)
    #pragma unroll
    for(int q=0;q<16;q++) acc[ct][q]=0.f;

  #pragma unroll
  for(int kc=0;kc<8;kc++){
    float v[8];
    if(aside){
      const float* src = A + (size_t)(k+128+rel)*1024 + k + kc*16 + hi*8;
      float4 u0 = ((const float4*)src)[0];
      float4 u1 = ((const float4*)src)[1];
      v[0]=u0.x; v[1]=u0.y; v[2]=u0.z; v[3]=u0.w;
      v[4]=u1.x; v[5]=u1.y; v[6]=u1.z; v[7]=u1.w;
    } else {
      const float* src = A + (size_t)(k + kc*16 + hi*8)*1024 + (k+128+rel);
      #pragma unroll
      for(int e=0;e<8;e++) v[e] = src[(size_t)e*1024];
    }
    bfrag ah, al;
    #pragma unroll
    for(int e=0;e<8;e++){
      unsigned short h = bf16rn(v[e]);
      ah[e] = (short)h;
      al[e] = (short)bf16rn(v[e] - bf2f(h));
    }
    #pragma unroll
    for(int ct=0;ct<4;ct++){
      bfrag bh = *(const bfrag*)(IH + (size_t)(ct*32+r32)*128 + kc*16 + hi*8);
      bfrag bl = *(const bfrag*)(IL + (size_t)(ct*32+r32)*128 + kc*16 + hi*8);
      acc[ct] = __builtin_amdgcn_mfma_f32_32x32x16_bf16(ah, bh, acc[ct], 0,0,0);
      acc[ct] = __builtin_amdgcn_mfma_f32_32x32x16_bf16(ah, bl, acc[ct], 0,0,0);
      acc[ct] = __builtin_amdgcn_mfma_f32_32x32x16_bf16(al, bh, acc[ct], 0,0,0);
    }
  }

  unsigned short* PH = (aside ? Ah : Bh) + (size_t)m*PANSZ;
  unsigned short* PL = (aside ? Al : Bl) + (size_t)m*PANSZ;
  #pragma unroll
  for(int ct=0;ct<4;ct++){
    #pragma unroll
    for(int reg=0;reg<16;reg++){
      int crow = (reg&3) + ((reg>>2)<<3) + (hi<<2);
      int r = tile0 + crow;
      float v = acc[ct][reg];
      unsigned short h = bf16rn(v);
      size_t off = (size_t)r*128 + ct*32 + r32;
      PH[off] = h;
      PL[off] = bf16rn(v - bf2f(h));
    }
  }
}

// ------------------------------------------------------- MFMA split-bf16 Schur
// A22 -= L21 * U12, K=128 in 4 staged 32-chunks.  128x128 C tile, 4 waves.
__global__ void __launch_bounds__(256) k_gemm(float* __restrict__ mats,
    const unsigned short* __restrict__ Ah, const unsigned short* __restrict__ Al,
    const unsigned short* __restrict__ Bh, const unsigned short* __restrict__ Bl,
    int k){
  int m = blockIdx.z;
  float* A = mats + (size_t)m*MSZ;
  int i0rel = blockIdx.y*128;
  int j0rel = blockIdx.x*128;
  __shared__ unsigned short As[2][4096];   // [hi/lo][row*32 + swz(koct)*8]
  __shared__ unsigned short Bs[2][4096];
  int t = threadIdx.x;
  int lane = t & 63, wvi = t >> 6;
  int wr = wvi >> 1, wc = wvi & 1;

  const unsigned short* pAh = Ah + (size_t)m*PANSZ;
  const unsigned short* pAl = Al + (size_t)m*PANSZ;
  const unsigned short* pBh = Bh + (size_t)m*PANSZ;
  const unsigned short* pBl = Bl + (size_t)m*PANSZ;

  int ldsOff[2];
  size_t offA[2], offB[2];
  #pragma unroll
  for(int p=0;p<2;p++){
    int c = t + 256*p;
    int row = c>>2, koct = c&3;
    ldsOff[p] = row*32 + ((koct ^ ((row>>1)&3))<<3);
    offA[p] = (size_t)(i0rel+row)*128 + koct*8;
    offB[p] = (size_t)(j0rel+row)*128 + koct*8;
  }

  #pragma unroll
  for(int p=0;p<2;p++){
    u16x8 a0 = *(const u16x8*)(pAh + offA[p]);
    u16x8 a1 = *(const u16x8*)(pAl + offA[p]);
    u16x8 b0 = *(const u16x8*)(pBh + offB[p]);
    u16x8 b1 = *(const u16x8*)(pBl + offB[p]);
    *(u16x8*)&As[0][ldsOff[p]] = a0;
    *(u16x8*)&As[1][ldsOff[p]] = a1;
    *(u16x8*)&Bs[0][ldsOff[p]] = b0;
    *(u16x8*)&Bs[1][ldsOff[p]] = b1;
  }
  u16x8 p1[8];
  #pragma unroll
  for(int p=0;p<2;p++){
    p1[4*p+0] = *(const u16x8*)(pAh + offA[p] + 32);
    p1[4*p+1] = *(const u16x8*)(pAl + offA[p] + 32);
    p1[4*p+2] = *(const u16x8*)(pBh + offB[p] + 32);
    p1[4*p+3] = *(const u16x8*)(pBl + offB[p] + 32);
  }
  __syncthreads();

  f32x16 acc[2][2];
  #pragma unroll
  for(int rt=0;rt<2;rt++)
    #pragma unroll
    for(int ct=0;ct<2;ct++)
      #pragma unroll
      for(int q=0;q<16;q++) acc[rt][ct][q] = 0.f;

  int kgrp = lane >> 5;
  #pragma unroll
  for(int st=0; st<4; st++){
    #pragma unroll
    for(int kc=0;kc<2;kc++){
      int koct = kc*2 + kgrp;
      bfrag ah[2], al[2], bh[2], bl[2];
      #pragma unroll
      for(int rt=0;rt<2;rt++){
        int row = wr*64 + rt*32 + (lane&31);
        int ad = row*32 + ((koct ^ ((row>>1)&3))<<3);
        ah[rt] = *(const bfrag*)&As[0][ad];
        al[rt] = *(const bfrag*)&As[1][ad];
      }
      #pragma unroll
      for(int ct=0;ct<2;ct++){
        int col = wc*64 + ct*32 + (lane&31);
        int ad = col*32 + ((koct ^ ((col>>1)&3))<<3);
        bh[ct] = *(const bfrag*)&Bs[0][ad];
        bl[ct] = *(const bfrag*)&Bs[1][ad];
      }
      #pragma unroll
      for(int rt=0;rt<2;rt++)
        #pragma unroll
        for(int ct=0;ct<2;ct++){
          acc[rt][ct] = __builtin_amdgcn_mfma_f32_32x32x16_bf16(ah[rt], bh[ct], acc[rt][ct], 0,0,0);
          acc[rt][ct] = __builtin_amdgcn_mfma_f32_32x32x16_bf16(ah[rt], bl[ct], acc[rt][ct], 0,0,0);
          acc[rt][ct] = __builtin_amdgcn_mfma_f32_32x32x16_bf16(al[rt], bh[ct], acc[rt][ct], 0,0,0);
        }
    }
    if(st<3){
      __syncthreads();
      #pragma unroll
      for(int p=0;p<2;p++){
        *(u16x8*)&As[0][ldsOff[p]] = p1[4*p+0];
        *(u16x8*)&As[1][ldsOff[p]] = p1[4*p+1];
        *(u16x8*)&Bs[0][ldsOff[p]] = p1[4*p+2];
        *(u16x8*)&Bs[1][ldsOff[p]] = p1[4*p+3];
      }
      if(st<2){
        #pragma unroll
        for(int p=0;p<2;p++){
          p1[4*p+0] = *(const u16x8*)(pAh + offA[p] + (st+2)*32);
          p1[4*p+1] = *(const u16x8*)(pAl + offA[p] + (st+2)*32);
          p1[4*p+2] = *(const u16x8*)(pBh + offB[p] + (st+2)*32);
          p1[4*p+3] = *(const u16x8*)(pBl + offB[p] + (st+2)*32);
        }
      }
      __syncthreads();
    }
  }

  int r0 = k + 128;
  #pragma unroll
  for(int rt=0;rt<2;rt++){
    int rowblk = i0rel + wr*64 + rt*32;
    #pragma unroll
    for(int ct=0;ct<2;ct++){
      int colblk = j0rel + wc*64 + ct*32;
      int col = r0 + colblk + (lane&31);
      int rbase = r0 + rowblk + ((lane>>5)<<2);
      #pragma unroll
      for(int reg=0;reg<16;reg++){
        int row = rbase + (reg&3) + ((reg>>2)<<3);
        float* pc = A + (size_t)row*1024 + col;
        *pc -= acc[rt][ct][reg];
      }
    }
  }
}

__global__ void k_final(const float* __restrict__ y, const float* __restrict__ logdet,
                        float* __restrict__ out){
  int b = threadIdx.x;
  if(b<32) out[b] = y[b] + logdet[1+b] - logdet[0];
}

// ---------------------------------------------------------------- launch
extern "C" void kernel_launch(void* const* d_in, const int* in_sizes, int n_in,
                              void* d_out, int out_size, void* d_ws, size_t ws_size,
                              hipStream_t stream){
  (void)in_sizes; (void)n_in; (void)out_size; (void)ws_size;
  const int*   x  = (const int*)d_in[0];
  const float* W  = (const float*)d_in[1];
  const float* Vc = (const float*)d_in[2];
  const float* Ec = (const float*)d_in[3];
  float* out = (float*)d_out;

  char* p = (char*)d_ws;
  auto alloc = [&](size_t bytes)->char*{ char* r = p; p += (bytes+255)&~(size_t)255; return r; };
  float* mats   = (float*)alloc((size_t)NMAT*MSZ*4);              // 138.4 MB
  float* Ws     = (float*)alloc(1048576ull*4);
  unsigned short* Ah = (unsigned short*)alloc((size_t)NMAT*PANSZ*2);
  unsigned short* Al = (unsigned short*)alloc((size_t)NMAT*PANSZ*2);
  unsigned short* Bh = (unsigned short*)alloc((size_t)NMAT*PANSZ*2);
  unsigned short* Bl = (unsigned short*)alloc((size_t)NMAT*PANSZ*2);
  unsigned short* UiH = (unsigned short*)alloc((size_t)NMAT*16384*2);  // 1 MB each
  unsigned short* UiL = (unsigned short*)alloc((size_t)NMAT*16384*2);
  unsigned short* LiH = (unsigned short*)alloc((size_t)NMAT*16384*2);
  unsigned short* LiL = (unsigned short*)alloc((size_t)NMAT*16384*2);
  float* V      = (float*)alloc(4096*4);
  float* PrInv  = (float*)alloc(32768*4);
  float* partial= (float*)alloc((size_t)32*16384*4);              // 2 MB
  float* y      = (float*)alloc(256);
  float* logdet = (float*)alloc(256);

  k_misc<<<4100,256,0,stream>>>(Vc, V, W, Ws);
  k_pr_y<<<32,256,0,stream>>>(V, x, PrInv, y);
  k_sinkhorn<<<4096,256,0,stream>>>(Ec, V, Ws, PrInv, x, mats, partial);
  k_l0<<<1024,256,0,stream>>>(Ws, mats);
  k_patch<<<dim3(4,32),256,0,stream>>>(mats, partial);

  k_diag<<<NMAT,256,0,stream>>>(mats, UiH,UiL,LiH,LiL, logdet, 0, 1);
  for(int s=0;s<7;s++){
    int k = 128*s;
    int rem = 1024 - (k+128);
    int nb = rem/128;
    k_trsm<<<dim3(2*nb,NMAT),256,0,stream>>>(mats, UiH,UiL,LiH,LiL, Ah,Al,Bh,Bl, k);
    k_gemm<<<dim3(nb,nb,NMAT),256,0,stream>>>(mats, Ah,Al,Bh,Bl, k);
    k_diag<<<NMAT,256,0,stream>>>(mats, UiH,UiL,LiH,LiL, logdet, k+128, (s<6)?1:0);
  }
  k_final<<<1,32,0,stream>>>(y, logdet, out);
}